// Round 6
// baseline (368.041 us; speedup 1.0000x reference)
//
#include <hip/hip_runtime.h>

#define DEV __device__ __forceinline__

typedef __attribute__((ext_vector_type(8))) short bf16x8;
typedef __attribute__((ext_vector_type(4))) float f32x4;

DEV float4 ld4(const float* p){ return *reinterpret_cast<const float4*>(p); }

DEV unsigned short f2bf(float f){
    union { float f; unsigned u; } v; v.f = f;
    unsigned r = v.u + 0x7fffu + ((v.u >> 16) & 1u);   // round-to-nearest-even
    return (unsigned short)(r >> 16);
}
DEV float bf2f(unsigned short s){
    union { unsigned u; float f; } v; v.u = ((unsigned)s) << 16;
    return v.f;
}

// bijective XCD-chunk swizzle (m204): contiguous work chunk per XCD
DEV int xcd_swizzle(int orig, int nwg){
    int q = nwg >> 3, r = nwg & 7;
    int x = orig & 7, i = orig >> 3;
    return (x < r ? x*(q+1) : r*(q+1) + (x-r)*q) + i;
}

// ---------------- inverse kernel-map build ----------------
__global__ __launch_bounds__(256)
void inv_init(int* __restrict__ inv, long n, int defv){
    long i = (long)blockIdx.x*256 + threadIdx.x;
    if (i < n) inv[i] = defv;
}

__global__ __launch_bounds__(256)
void inv_build(const int* __restrict__ inK, const int* __restrict__ outK,
               int* __restrict__ inv, int M, int n_out){
    int k = blockIdx.y;
    int m = blockIdx.x*256 + threadIdx.x;
    if (m >= M) return;
    int o = outK[(long)k*M + m];
    if (o != n_out) inv[(long)k*n_out + o] = inK[(long)k*M + m];  // o unique per offset
}

// zero the sentinel rows (row n_out) of the bf16 feature buffers
__global__ __launch_bounds__(256)
void zero_rows(unsigned short* A, unsigned short* B, unsigned short* C,
               unsigned short* D, unsigned short* E, int n_out){
    int t = threadIdx.x;
    if (t < 64)       A[(long)n_out*64 + t] = 0;
    else if (t < 80)  B[(long)n_out*16 + (t-64)] = 0;
    else if (t < 144) C[(long)n_out*64 + (t-80)] = 0;
    else if (t < 160) D[(long)n_out*16 + (t-144)] = 0;
    else if (t < 176) E[(long)n_out*16 + (t-160)] = 0;
}

// ---------------- W -> fragment-layout bf16 conversion ----------------
__global__ __launch_bounds__(256)
void wfrag_unpaired(const float* __restrict__ W, unsigned short* __restrict__ F,
                    int KC, int NT, int CIN, int CR, int total){
    int idx = blockIdx.x*256 + threadIdx.x;
    if (idx >= total) return;
    int j = idx & 7, l = (idx >> 3) & 63, rest = idx >> 9;
    int nt = rest % NT, cc = rest / NT;
    int k = cc / KC, kc = cc % KC;
    int g = l >> 4, c = l & 15;
    int cin = kc*32 + g*8 + j, cout = nt*16 + c;
    float v = (cout < CR) ? W[((long)k*CIN + cin)*CR + cout] : 0.f;
    F[idx] = f2bf(v);
}

__global__ __launch_bounds__(256)
void wfrag_paired(const float* __restrict__ W, unsigned short* __restrict__ F,
                  int NKr, int NT, int CR, int total){
    int idx = blockIdx.x*256 + threadIdx.x;
    if (idx >= total) return;
    int j = idx & 7, l = (idx >> 3) & 63, rest = idx >> 9;
    int nt = rest % NT, cc = rest / NT;
    int g = l >> 4, c = l & 15;
    int koff = 2*cc + (g >> 1);
    int cin = (g & 1)*8 + j, cout = nt*16 + c;
    float v = (koff < NKr && cout < CR) ? W[((long)koff*16 + cin)*CR + cout] : 0.f;
    F[idx] = f2bf(v);
}

// ---------------- gather MFMA conv ----------------
// MODE 0: inv-gather, NK offsets x KC K32-chunks, bf16 X rows of RB bytes (branchless zero-row,
//         sentinel = n_out -> zeroed row of X)
// MODE 1: paired inv-gather (CIN=16): NK chunk-pairs, offset = 2c + (g>>1) (branchless zero-row)
// MODE 4: conv1 inv-gather, A from TWO fp32 arrays (kc<2: xF, else ctxF), masked (b >= 0,
//         sentinel = -1: inv1 values live in [0, n_in) and n_in > n_out!)
template<int MODE, int NK, int G, int KC, int NT, int RB, bool RELU, int RESBASE,
         bool OUTBF16, int YS, int CB, int CR, int WPE>
__global__ __launch_bounds__(256, WPE)
void mfma_gather(const void* __restrict__ Xv,
                 const float* __restrict__ xF, const float* __restrict__ cF,
                 const unsigned short* __restrict__ Wf, const int* __restrict__ inv,
                 const float* __restrict__ bias, const unsigned short* __restrict__ RES,
                 void* __restrict__ Yv, int n_out)
{
    const int bid = xcd_swizzle(blockIdx.x, gridDim.x);
    const int lane = threadIdx.x & 63, wave = threadIdx.x >> 6;
    const int jbase = (bid*4 + wave)*32;      // 32 rows per wave
    if (jbase >= n_out) return;
    const int r = lane & 15, g = lane >> 4;
    const int jrow0 = jbase + r, jrow1 = jbase + 16 + r;
    const int jc0 = min(jrow0, n_out-1), jc1 = min(jrow1, n_out-1);  // clamp for inv reads
    const char* X = (const char*)Xv;
    const bf16x8* __restrict__ WF = (const bf16x8*)Wf;
    const bf16x8 az = {0,0,0,0,0,0,0,0};
    f32x4 acc0[NT], acc1[NT];
    #pragma unroll
    for (int nt=0; nt<NT; ++nt){ acc0[nt] = f32x4{0,0,0,0}; acc1[nt] = f32x4{0,0,0,0}; }

    #pragma unroll 1
    for (int g0 = 0; g0 < NK; g0 += G) {
        int b0[G], b1[G];
        #pragma unroll
        for (int kk=0; kk<G; ++kk){
            if constexpr (MODE == 1) {
                int koff = 2*(g0+kk) + (g >> 1);
                b0[kk] = inv[(long)koff*n_out + jc0];
                b1[kk] = inv[(long)koff*n_out + jc1];
            } else {
                b0[kk] = inv[(long)(g0+kk)*n_out + jc0];
                b1[kk] = inv[(long)(g0+kk)*n_out + jc1];
            }
        }
        #pragma unroll
        for (int kk=0; kk<G; ++kk){
            const int k = g0 + kk;
            if constexpr (MODE == 1) {
                bf16x8 a0 = *(const bf16x8*)(X + (long)b0[kk]*RB + (g&1)*16);
                bf16x8 a1 = *(const bf16x8*)(X + (long)b1[kk]*RB + (g&1)*16);
                #pragma unroll
                for (int nt=0; nt<NT; ++nt){
                    bf16x8 w = WF[((long)k*NT + nt)*64 + lane];
                    acc0[nt] = __builtin_amdgcn_mfma_f32_16x16x32_bf16(a0, w, acc0[nt], 0, 0, 0);
                    acc1[nt] = __builtin_amdgcn_mfma_f32_16x16x32_bf16(a1, w, acc1[nt], 0, 0, 0);
                }
            } else if constexpr (MODE == 0) {
                #pragma unroll
                for (int kc=0; kc<KC; ++kc){
                    bf16x8 a0 = *(const bf16x8*)(X + (long)b0[kk]*RB + kc*64 + g*16);
                    bf16x8 a1 = *(const bf16x8*)(X + (long)b1[kk]*RB + kc*64 + g*16);
                    #pragma unroll
                    for (int nt=0; nt<NT; ++nt){
                        bf16x8 w = WF[((long)(k*KC+kc)*NT + nt)*64 + lane];
                        acc0[nt] = __builtin_amdgcn_mfma_f32_16x16x32_bf16(a0, w, acc0[nt], 0, 0, 0);
                        acc1[nt] = __builtin_amdgcn_mfma_f32_16x16x32_bf16(a1, w, acc1[nt], 0, 0, 0);
                    }
                }
            } else { // MODE 4 (sentinel -1; valid b may be any index in [0, n_in))
                #pragma unroll
                for (int kc=0; kc<KC; ++kc){
                    bf16x8 a0 = az, a1 = az;
                    if (b0[kk] >= 0) {
                        const float* s = (kc < 2) ? (xF + (long)b0[kk]*64 + kc*32 + g*8)
                                                  : (cF + (long)b0[kk]*64 + (kc-2)*32 + g*8);
                        float4 lo = ld4(s), hi = ld4(s+4);
                        a0[0]=(short)f2bf(lo.x); a0[1]=(short)f2bf(lo.y);
                        a0[2]=(short)f2bf(lo.z); a0[3]=(short)f2bf(lo.w);
                        a0[4]=(short)f2bf(hi.x); a0[5]=(short)f2bf(hi.y);
                        a0[6]=(short)f2bf(hi.z); a0[7]=(short)f2bf(hi.w);
                    }
                    if (b1[kk] >= 0) {
                        const float* s = (kc < 2) ? (xF + (long)b1[kk]*64 + kc*32 + g*8)
                                                  : (cF + (long)b1[kk]*64 + (kc-2)*32 + g*8);
                        float4 lo = ld4(s), hi = ld4(s+4);
                        a1[0]=(short)f2bf(lo.x); a1[1]=(short)f2bf(lo.y);
                        a1[2]=(short)f2bf(lo.z); a1[3]=(short)f2bf(lo.w);
                        a1[4]=(short)f2bf(hi.x); a1[5]=(short)f2bf(hi.y);
                        a1[6]=(short)f2bf(hi.z); a1[7]=(short)f2bf(hi.w);
                    }
                    #pragma unroll
                    for (int nt=0; nt<NT; ++nt){
                        bf16x8 w = WF[((long)(k*KC+kc)*NT + nt)*64 + lane];
                        acc0[nt] = __builtin_amdgcn_mfma_f32_16x16x32_bf16(a0, w, acc0[nt], 0, 0, 0);
                        acc1[nt] = __builtin_amdgcn_mfma_f32_16x16x32_bf16(a1, w, acc1[nt], 0, 0, 0);
                    }
                }
            }
        }
    }

    // epilogue: D layout col = lane&15, row = (lane>>4)*4 + q  [m89-verified]
    float bi[NT];
    #pragma unroll
    for (int nt=0; nt<NT; ++nt){
        int c = nt*16 + r;
        bi[nt] = (c < CR) ? bias[c] : 0.f;
    }
    #pragma unroll
    for (int q=0; q<4; ++q){
        int row = jbase + g*4 + q;
        if (row < n_out){
            #pragma unroll
            for (int nt=0; nt<NT; ++nt){
                int c = nt*16 + r;
                float v = acc0[nt][q] + bi[nt];
                if constexpr (RESBASE >= 0) v += bf2f(RES[(long)row*64 + RESBASE + c]);
                if constexpr (RELU) v = fmaxf(v, 0.f);
                if constexpr (OUTBF16) ((unsigned short*)Yv)[(long)row*YS + CB + c] = f2bf(v);
                else if (c < CR)       ((float*)Yv)[(long)row*YS + CB + c] = v;
            }
        }
    }
    #pragma unroll
    for (int q=0; q<4; ++q){
        int row = jbase + 16 + g*4 + q;
        if (row < n_out){
            #pragma unroll
            for (int nt=0; nt<NT; ++nt){
                int c = nt*16 + r;
                float v = acc1[nt][q] + bi[nt];
                if constexpr (RESBASE >= 0) v += bf2f(RES[(long)row*64 + RESBASE + c]);
                if constexpr (RELU) v = fmaxf(v, 0.f);
                if constexpr (OUTBF16) ((unsigned short*)Yv)[(long)row*YS + CB + c] = f2bf(v);
                else if (c < CR)       ((float*)Yv)[(long)row*YS + CB + c] = v;
            }
        }
    }
}

// ---------------- identity-mode MFMA (dense 1x1s) ----------------
// MODE 2: identity (CIN=64); MODE 3: identity-paired (CIN=16), groups >=2 zero
template<int MODE, int NT, int RB, bool RELU, int RESBASE,
         bool OUTBF16, int YS, int CB, int CR>
__global__ __launch_bounds__(256)
void mfma_dense(const void* __restrict__ Xv,
                const unsigned short* __restrict__ Wf,
                const float* __restrict__ bias, const unsigned short* __restrict__ RES,
                void* __restrict__ Yv, int n_out)
{
    const int lane = threadIdx.x & 63, wave = threadIdx.x >> 6;
    const int jbase = (blockIdx.x*4 + wave)*16;
    if (jbase >= n_out) return;
    const int r = lane & 15, g = lane >> 4;
    const int jrow = jbase + r;
    const bool rowok = jrow < n_out;
    const char* X = (const char*)Xv;
    const bf16x8* __restrict__ WF = (const bf16x8*)Wf;
    const bf16x8 az = {0,0,0,0,0,0,0,0};
    f32x4 acc[NT];
    #pragma unroll
    for (int nt=0; nt<NT; ++nt) acc[nt] = f32x4{0,0,0,0};

    if constexpr (MODE == 2) {
        #pragma unroll
        for (int kc=0; kc<2; ++kc){
            bf16x8 a = az;
            if (rowok) a = *(const bf16x8*)(X + (long)jrow*RB + kc*64 + g*16);
            #pragma unroll
            for (int nt=0; nt<NT; ++nt){
                bf16x8 w = WF[((long)kc*NT + nt)*64 + lane];
                acc[nt] = __builtin_amdgcn_mfma_f32_16x16x32_bf16(a, w, acc[nt], 0, 0, 0);
            }
        }
    } else {
        bf16x8 a = az;
        if (rowok && g < 2) a = *(const bf16x8*)(X + (long)jrow*RB + (g&1)*16);
        #pragma unroll
        for (int nt=0; nt<NT; ++nt){
            bf16x8 w = WF[nt*64 + lane];
            acc[nt] = __builtin_amdgcn_mfma_f32_16x16x32_bf16(a, w, acc[nt], 0, 0, 0);
        }
    }

    float bi[NT];
    #pragma unroll
    for (int nt=0; nt<NT; ++nt){
        int c = nt*16 + r;
        bi[nt] = (c < CR) ? bias[c] : 0.f;
    }
    #pragma unroll
    for (int q=0; q<4; ++q){
        int row = jbase + g*4 + q;
        if (row < n_out){
            #pragma unroll
            for (int nt=0; nt<NT; ++nt){
                int c = nt*16 + r;
                float v = acc[nt][q] + bi[nt];
                if constexpr (RESBASE >= 0) v += bf2f(RES[(long)row*64 + RESBASE + c]);
                if constexpr (RELU) v = fmaxf(v, 0.f);
                if constexpr (OUTBF16) ((unsigned short*)Yv)[(long)row*YS + CB + c] = f2bf(v);
                else if (c < CR)       ((float*)Yv)[(long)row*YS + CB + c] = v;
            }
        }
    }
}

extern "C" void kernel_launch(void* const* d_in, const int* in_sizes, int n_in_cnt,
                              void* d_out, int out_size, void* d_ws, size_t ws_size,
                              hipStream_t stream)
{
    const float* xF   = (const float*)d_in[0];
    const float* ctxF = (const float*)d_in[1];
    const float* W1   = (const float*)d_in[2];
    const float* b1   = (const float*)d_in[3];
    const float* Wr00 = (const float*)d_in[4];
    const float* br00 = (const float*)d_in[5];
    const float* Wr01 = (const float*)d_in[6];
    const float* br01 = (const float*)d_in[7];
    const float* Wr10 = (const float*)d_in[8];
    const float* br10 = (const float*)d_in[9];
    const float* Wr11 = (const float*)d_in[10];
    const float* br11 = (const float*)d_in[11];
    const float* Wr12 = (const float*)d_in[12];
    const float* br12 = (const float*)d_in[13];
    const float* W2   = (const float*)d_in[14];
    const float* b2   = (const float*)d_in[15];
    const int* in1  = (const int*)d_in[16];
    const int* out1 = (const int*)d_in[17];
    const int* in3  = (const int*)d_in[18];
    const int* out3 = (const int*)d_in[19];

    const int n_out = out_size / 8;          // CL = 8
    const int M1 = in_sizes[16] / 8;
    const int M3 = in_sizes[18] / 27;

    char* p = (char*)d_ws;
    int* inv3 = (int*)p;                 p += (size_t)28*n_out*4;   // 27 built + 1 pad row
    int* inv1 = (int*)p;                 p += (size_t)8*n_out*4;
    unsigned short* A = (unsigned short*)p;  p += (size_t)(n_out+1)*64*2;
    unsigned short* B = (unsigned short*)p;  p += (size_t)(n_out+1)*16*2;
    unsigned short* C = (unsigned short*)p;  p += (size_t)(n_out+1)*64*2;
    unsigned short* D = (unsigned short*)p;  p += (size_t)(n_out+1)*16*2;
    unsigned short* E = (unsigned short*)p;  p += (size_t)(n_out+1)*16*2;
    unsigned short* Wf_c1 = (unsigned short*)p;  p += (size_t)32*4*512*2;
    unsigned short* Wf_00 = (unsigned short*)p;  p += (size_t)54*512*2;
    unsigned short* Wf_2  = (unsigned short*)p;  p += (size_t)54*512*2;
    unsigned short* Wf_01 = (unsigned short*)p;  p += (size_t)14*2*512*2;
    unsigned short* Wf_11 = (unsigned short*)p;  p += (size_t)14*512*2;
    unsigned short* Wf_10 = (unsigned short*)p;  p += (size_t)2*512*2;
    unsigned short* Wf_12 = (unsigned short*)p;  p += (size_t)2*512*2;
    float* OUT = (float*)d_out;

    auto cdiv = [](long a, long b){ return (int)((a + b - 1)/b); };

    // inverse kernel maps.
    // inv3 sentinel = n_out (zero-row trick; in3 values are in [0, n_out)).
    // inv1 sentinel = -1 (in1 values are in [0, n_in) and n_in > n_out — n_out is a VALID index!).
    inv_init<<<cdiv((long)28*n_out,256),256,0,stream>>>(inv3, (long)28*n_out, n_out);
    inv_init<<<cdiv((long)8*n_out,256),256,0,stream>>>(inv1, (long)8*n_out, -1);
    inv_build<<<dim3(cdiv(M3,256),27),256,0,stream>>>(in3, out3, inv3, M3, n_out);
    inv_build<<<dim3(cdiv(M1,256),8),256,0,stream>>>(in1, out1, inv1, M1, n_out);
    zero_rows<<<1,256,0,stream>>>(A, B, C, D, E, n_out);

    // weight fragment conversion
    wfrag_unpaired<<<cdiv(32*4*512,256),256,0,stream>>>(W1,   Wf_c1, 4, 4, 128, 64, 32*4*512);
    wfrag_unpaired<<<cdiv(54*512,256),  256,0,stream>>>(Wr00, Wf_00, 2, 1,  64, 16, 54*512);
    wfrag_unpaired<<<cdiv(54*512,256),  256,0,stream>>>(W2,   Wf_2,  2, 1,  64,  8, 54*512);
    wfrag_unpaired<<<cdiv(2*512,256),   256,0,stream>>>(Wr10, Wf_10, 2, 1,  64, 16, 2*512);
    wfrag_paired  <<<cdiv(14*2*512,256),256,0,stream>>>(Wr01, Wf_01, 27, 2, 32, 14*2*512);
    wfrag_paired  <<<cdiv(14*512,256),  256,0,stream>>>(Wr11, Wf_11, 27, 1, 16, 14*512);
    wfrag_paired  <<<cdiv(2*512,256),   256,0,stream>>>(Wr12, Wf_12,  1, 2, 32, 2*512);

    const int grid_g = cdiv(n_out, 128);   // 4 waves/block, 32 rows/wave
    const int grid_d = cdiv(n_out, 64);    // 4 waves/block, 16 rows/wave

    // conv1: A = bf16( b1 + sum_k [xF|ctxF][inv1[k]] @ W1[k] )
    mfma_gather<4, 8,8,4,4, 0, false, -1, true, 64, 0, 64, 3>
        <<<grid_g,256,0,stream>>>(nullptr, xF, ctxF, Wf_c1, inv1, b1, nullptr, A, n_out);
    // B = relu(sconv(A, Wr00) + br00)
    mfma_gather<0, 27,9,2,1, 128, true, -1, true, 16, 0, 16, 4>
        <<<grid_g,256,0,stream>>>(A, nullptr, nullptr, Wf_00, inv3, br00, nullptr, B, n_out);
    // D = relu(A @ Wr10 + br10)
    mfma_dense<2, 1, 128, true, -1, true, 16, 0, 16>
        <<<grid_d,256,0,stream>>>(A, Wf_10, br10, nullptr, D, n_out);
    // C[:,0:32] = sconv(B, Wr01) + br01 + A[:,0:32]
    mfma_gather<1, 14,7,0,2, 32, false, 0, true, 64, 0, 32, 4>
        <<<grid_g,256,0,stream>>>(B, nullptr, nullptr, Wf_01, inv3, br01, A, C, n_out);
    // E = relu(sconv(D, Wr11) + br11)
    mfma_gather<1, 14,7,0,1, 32, true, -1, true, 16, 0, 16, 4>
        <<<grid_g,256,0,stream>>>(D, nullptr, nullptr, Wf_11, inv3, br11, nullptr, E, n_out);
    // C[:,32:64] = E @ Wr12 + br12 + A[:,32:64]
    mfma_dense<3, 2, 32, false, 32, true, 64, 32, 32>
        <<<grid_d,256,0,stream>>>(E, Wf_12, br12, A, C, n_out);
    // OUT = sconv(C, W2) + b2   (fp32, masked to 8 cols)
    mfma_gather<0, 27,9,2,1, 128, false, -1, false, 8, 0, 8, 4>
        <<<grid_g,256,0,stream>>>(C, nullptr, nullptr, Wf_2, inv3, b2, nullptr, OUT, n_out);
}